// Round 3
// baseline (1303.361 us; speedup 1.0000x reference)
//
#include <hip/hip_runtime.h>
#include <hip/hip_bf16.h>

#define DEV __device__ __forceinline__

typedef __attribute__((ext_vector_type(8))) short bf16x8;
typedef __attribute__((ext_vector_type(4))) float f32x4;
typedef __attribute__((ext_vector_type(4))) short short4v;

DEV short f2bf(float f) {
  union { float f; unsigned u; } z; z.f = f;
  unsigned r = z.u + 0x7fffu + ((z.u >> 16) & 1u);
  return (short)(r >> 16);
}
DEV float bf2f(short s) {
  union { unsigned u; float f; } z; z.u = ((unsigned)(unsigned short)s) << 16;
  return z.f;
}
DEV void split3_1(float x, short& b1, short& b2, short& b3) {
  b1 = f2bf(x); float r = x - bf2f(b1);
  b2 = f2bf(r); float r2 = r - bf2f(b2);
  b3 = f2bf(r2);
}
DEV void split3_8(const float* src, bf16x8& o1, bf16x8& o2, bf16x8& o3) {
  short a1[8], a2[8], a3[8];
  #pragma unroll
  for (int t = 0; t < 8; ++t) split3_1(src[t], a1[t], a2[t], a3[t]);
  o1 = *(bf16x8*)a1; o2 = *(bf16x8*)a2; o3 = *(bf16x8*)a3;
}

DEV f32x4 mfma16(bf16x8 a, bf16x8 b, f32x4 c) {
  return __builtin_amdgcn_mfma_f32_16x16x32_bf16(a, b, c, 0, 0, 0);
}
// bf16x3 6-pass: ~fp32-accurate product sum
DEV f32x4 mfma6(bf16x8 a1, bf16x8 a2, bf16x8 a3,
                bf16x8 b1, bf16x8 b2, bf16x8 b3, f32x4 c) {
  c = mfma16(a1, b1, c);
  c = mfma16(a1, b2, c);
  c = mfma16(a2, b1, c);
  c = mfma16(a1, b3, c);
  c = mfma16(a2, b2, c);
  c = mfma16(a3, b1, c);
  return c;
}

DEV void gll16(const short* g, short* l) {
  __builtin_amdgcn_global_load_lds(
      (const __attribute__((address_space(1))) void*)g,
      (__attribute__((address_space(3))) void*)l, 16, 0, 0);
}

DEV float gelu_exact(float x) {
  return 0.5f * x * (1.f + erff(x * 0.70710678118654752f));
}

// ---------------- weight fp32 -> bf16 (single plane, experts) ----------------
__global__ __launch_bounds__(256) void convert_kernel(const float* __restrict__ in,
                                                      short* __restrict__ out, int n8) {
  int i = blockIdx.x * 256 + threadIdx.x;
  if (i >= n8) return;
  const float4* p = (const float4*)(in) + (size_t)i * 2;
  float4 a = p[0], b = p[1];
  short o[8] = { f2bf(a.x), f2bf(a.y), f2bf(a.z), f2bf(a.w),
                 f2bf(b.x), f2bf(b.y), f2bf(b.z), f2bf(b.w) };
  *(bf16x8*)(out + (size_t)i * 8) = *(bf16x8*)o;
}

// ---------------- weight fp32 -> 3 bf16 planes (attention path) ----------------
__global__ __launch_bounds__(256) void split_kernel(const float* __restrict__ in,
                                                    short* __restrict__ out,
                                                    size_t pstride, int n8) {
  int i = blockIdx.x * 256 + threadIdx.x;
  if (i >= n8) return;
  float buf[8];
  *(float4*)buf       = ((const float4*)in)[(size_t)i * 2];
  *(float4*)(buf + 4) = ((const float4*)in)[(size_t)i * 2 + 1];
  bf16x8 o1, o2, o3; split3_8(buf, o1, o2, o3);
  *(bf16x8*)(out + (size_t)i * 8) = o1;
  *(bf16x8*)(out + pstride + (size_t)i * 8) = o2;
  *(bf16x8*)(out + 2 * pstride + (size_t)i * 8) = o3;
}

// ---------------- LayerNorm fp32 -> bf16 (1 plane or 3 split planes) ----------------
template<int NSPLIT>
__global__ __launch_bounds__(256) void ln_kernel(const float* __restrict__ X,
    const float* __restrict__ gam, const float* __restrict__ bet,
    short* __restrict__ Y, size_t pstride) {
  int row = blockIdx.x;
  int tid = threadIdx.x;
  float4 v = ((const float4*)(X + (size_t)row * 1024))[tid];
  float s = v.x + v.y + v.z + v.w;
  float s2 = v.x*v.x + v.y*v.y + v.z*v.z + v.w*v.w;
  #pragma unroll
  for (int d = 1; d < 64; d <<= 1) { s += __shfl_xor(s, d); s2 += __shfl_xor(s2, d); }
  __shared__ float a1[4], a2[4];
  int w = tid >> 6;
  if ((tid & 63) == 0) { a1[w] = s; a2[w] = s2; }
  __syncthreads();
  s = a1[0] + a1[1] + a1[2] + a1[3];
  s2 = a2[0] + a2[1] + a2[2] + a2[3];
  float mean = s * 0.0009765625f;
  float var = s2 * 0.0009765625f - mean * mean;
  float inv = rsqrtf(var + 1e-5f);
  float4 g4 = ((const float4*)gam)[tid];
  float4 b4 = ((const float4*)bet)[tid];
  float o[4] = { (v.x-mean)*inv*g4.x + b4.x, (v.y-mean)*inv*g4.y + b4.y,
                 (v.z-mean)*inv*g4.z + b4.z, (v.w-mean)*inv*g4.w + b4.w };
  if (NSPLIT == 1) {
    short q[4] = { f2bf(o[0]), f2bf(o[1]), f2bf(o[2]), f2bf(o[3]) };
    *(short4v*)(Y + (size_t)row*1024 + tid*4) = *(short4v*)q;
  } else {
    short q1[4], q2[4], q3[4];
    #pragma unroll
    for (int t = 0; t < 4; ++t) split3_1(o[t], q1[t], q2[t], q3[t]);
    size_t off = (size_t)row*1024 + tid*4;
    *(short4v*)(Y + off) = *(short4v*)q1;
    *(short4v*)(Y + pstride + off) = *(short4v*)q2;
    *(short4v*)(Y + 2*pstride + off) = *(short4v*)q3;
  }
}

// ---------------- bf16x3 NT GEMM, 128x128 tile, BK=32 ----------------
// A planes [M][K], B planes [N][K]. MODE 0: store fp32 C. MODE 1: out = x + C + bias.
template<int MODE>
__global__ __launch_bounds__(256) void gemm3(
    const short* __restrict__ A, const short* __restrict__ B,
    size_t psA, size_t psB, int lda, int ldb, int nk,
    float* __restrict__ outf, int ldc,
    const float* __restrict__ xres, const float* __restrict__ bias) {
  __shared__ short As[3][128*32], Bs[3][128*32];
  const int n0 = blockIdx.x * 128, m0 = blockIdx.y * 128;
  const int tid = threadIdx.x, w = tid >> 6, lane = tid & 63;
  const int c0 = w*128 + lane, c1 = c0 + 64;
  const short* ga0 = A + (size_t)(m0 + (c0 >> 2)) * lda + (c0 & 3) * 8;
  const short* ga1 = A + (size_t)(m0 + (c1 >> 2)) * lda + (c1 & 3) * 8;
  const short* gb0 = B + (size_t)(n0 + (c0 >> 2)) * ldb + (c0 & 3) * 8;
  const short* gb1 = B + (size_t)(n0 + (c1 >> 2)) * ldb + (c1 & 3) * 8;
  const int lrow = lane & 15, lk8 = (lane >> 4) * 8;
  const int wr = w >> 1, wc = w & 1;
  f32x4 acc[4][4];
  #pragma unroll
  for (int m=0;m<4;++m)
    #pragma unroll
    for(int n=0;n<4;++n) acc[m][n] = f32x4{0.f,0.f,0.f,0.f};
  for (int kt = 0; kt < nk; ++kt) {
    __syncthreads();
    #pragma unroll
    for (int p = 0; p < 3; ++p) {
      gll16(ga0 + p*psA, &As[p][(w*128)*8]);
      gll16(ga1 + p*psA, &As[p][(w*128+64)*8]);
      gll16(gb0 + p*psB, &Bs[p][(w*128)*8]);
      gll16(gb1 + p*psB, &Bs[p][(w*128+64)*8]);
    }
    ga0 += 32; ga1 += 32; gb0 += 32; gb1 += 32;
    asm volatile("s_waitcnt vmcnt(0)" ::: "memory");
    __syncthreads();
    bf16x8 a[3][4], b[3][4];
    #pragma unroll
    for (int p = 0; p < 3; ++p) {
      #pragma unroll
      for (int m = 0; m < 4; ++m)
        a[p][m] = *(const bf16x8*)(&As[p][(wr*64 + m*16 + lrow)*32 + lk8]);
      #pragma unroll
      for (int n = 0; n < 4; ++n)
        b[p][n] = *(const bf16x8*)(&Bs[p][(wc*64 + n*16 + lrow)*32 + lk8]);
    }
    #pragma unroll
    for (int m = 0; m < 4; ++m)
      #pragma unroll
      for (int n = 0; n < 4; ++n)
        acc[m][n] = mfma6(a[0][m], a[1][m], a[2][m],
                          b[0][n], b[1][n], b[2][n], acc[m][n]);
  }
  const int lgp = lane >> 4;
  #pragma unroll
  for (int m=0;m<4;++m)
    #pragma unroll
    for (int n=0;n<4;++n)
      #pragma unroll
      for (int j=0;j<4;++j) {
        int row = m0 + wr*64 + m*16 + lgp*4 + j;
        int col = n0 + wc*64 + n*16 + lrow;
        float v = acc[m][n][j];
        if (MODE == 0) {
          outf[(size_t)row * ldc + col] = v;
        } else {
          outf[(size_t)row * 1024 + col] = xres[(size_t)row*1024 + col] + v + bias[col];
        }
      }
}

// ---------------- flash attention, bf16x3 precision, fp32 LDS tiles ----------------
__global__ __launch_bounds__(256) void attn_kernel(
    const float* __restrict__ qkv, short* __restrict__ y3, size_t psY) {
  const int qt = blockIdx.x, h = blockIdx.y, b = blockIdx.z;
  const int tid = threadIdx.x, w = tid >> 6, lane = tid & 63;
  const int lrow = lane & 15, lgp = lane >> 4;
  __shared__ float kl[64*68];
  __shared__ float vt[64*68];      // transposed [d][kk]
  __shared__ float pl[4][16*68];

  // Q fragment fp32 -> 3 bf16 splits (per lane: rows w*16+lrow, k = lgp*8 within halves)
  const float* qrow = qkv + (size_t)(b*1024 + qt*64 + w*16 + lrow)*3072 + h*64;
  bf16x8 q1[2], q2[2], q3[2];
  #pragma unroll
  for (int half = 0; half < 2; ++half) {
    float qbuf[8];
    *(float4*)qbuf     = *(const float4*)(qrow + half*32 + lgp*8);
    *(float4*)(qbuf+4) = *(const float4*)(qrow + half*32 + lgp*8 + 4);
    split3_8(qbuf, q1[half], q2[half], q3[half]);
  }

  f32x4 accY[4];
  #pragma unroll
  for (int dn=0;dn<4;++dn) accY[dn] = f32x4{0.f,0.f,0.f,0.f};
  float mrow[4] = {-1e30f,-1e30f,-1e30f,-1e30f};
  float lsum[4] = {0.f,0.f,0.f,0.f};

  for (int jt = 0; jt <= qt; ++jt) {
    __syncthreads();
    // stage K tile [64 keys][64 d] and V^T tile [64 d][64 keys] as fp32
    #pragma unroll
    for (int it = 0; it < 4; ++it) {
      int ch = it*256 + tid;
      int r = ch >> 4, cq = ch & 15;
      const float* src = qkv + (size_t)(b*1024 + jt*64 + r)*3072 + h*64 + 1024 + cq*4;
      float4 kv = *(const float4*)src;
      *(float4*)(kl + r*68 + cq*4) = kv;
      float4 vv = *(const float4*)(src + 1024);
      float va[4] = { vv.x, vv.y, vv.z, vv.w };
      #pragma unroll
      for (int u = 0; u < 4; ++u) {
        int uu = (u + tid) & 3;   // rotation spreads bank collisions
        float sv = (uu==0)?va[0]:((uu==1)?va[1]:((uu==2)?va[2]:va[3]));
        vt[(cq*4+uu)*68 + r] = sv;
      }
    }
    __syncthreads();

    // QK^T in bf16x3 (12 MFMA per kn)
    f32x4 sA[4];
    #pragma unroll
    for (int kn = 0; kn < 4; ++kn) {
      f32x4 z = f32x4{0.f,0.f,0.f,0.f};
      #pragma unroll
      for (int half = 0; half < 2; ++half) {
        bf16x8 k1, k2, k3;
        split3_8(kl + (kn*16 + lrow)*68 + half*32 + lgp*8, k1, k2, k3);
        z = mfma6(q1[half], q2[half], q3[half], k1, k2, k3, z);
      }
      sA[kn] = z;
    }
    const bool diag = (jt == qt);
    #pragma unroll
    for (int kn = 0; kn < 4; ++kn)
      #pragma unroll
      for (int j = 0; j < 4; ++j) {
        float sv = sA[kn][j] * 0.125f;
        if (diag && (kn*16 + lrow) > (w*16 + lgp*4 + j)) sv = -1e30f;
        sA[kn][j] = sv;
      }
    // online softmax (fp32)
    #pragma unroll
    for (int j = 0; j < 4; ++j) {
      float mx = fmaxf(fmaxf(sA[0][j], sA[1][j]), fmaxf(sA[2][j], sA[3][j]));
      mx = fmaxf(mx, __shfl_xor(mx, 1));
      mx = fmaxf(mx, __shfl_xor(mx, 2));
      mx = fmaxf(mx, __shfl_xor(mx, 4));
      mx = fmaxf(mx, __shfl_xor(mx, 8));
      float mnew = fmaxf(mrow[j], mx);
      float scal = __expf(mrow[j] - mnew);
      mrow[j] = mnew;
      float rs = 0.f;
      #pragma unroll
      for (int kn = 0; kn < 4; ++kn) {
        float pv = __expf(sA[kn][j] - mnew);
        sA[kn][j] = pv;
        rs += pv;
      }
      rs += __shfl_xor(rs, 1); rs += __shfl_xor(rs, 2);
      rs += __shfl_xor(rs, 4); rs += __shfl_xor(rs, 8);
      lsum[j] = lsum[j]*scal + rs;
      #pragma unroll
      for (int dn = 0; dn < 4; ++dn) accY[dn][j] *= scal;
    }
    // P (fp32) to wave-private LDS, then PV in bf16x3
    #pragma unroll
    for (int kn = 0; kn < 4; ++kn)
      #pragma unroll
      for (int j = 0; j < 4; ++j)
        pl[w][(lgp*4 + j)*68 + kn*16 + lrow] = sA[kn][j];
    __builtin_amdgcn_sched_barrier(0);
    #pragma unroll
    for (int ks = 0; ks < 2; ++ks) {
      bf16x8 p1, p2, p3;
      split3_8(&pl[w][lrow*68 + ks*32 + lgp*8], p1, p2, p3);
      #pragma unroll
      for (int dn = 0; dn < 4; ++dn) {
        bf16x8 v1, v2, v3;
        split3_8(vt + (dn*16 + lrow)*68 + ks*32 + lgp*8, v1, v2, v3);
        accY[dn] = mfma6(p1, p2, p3, v1, v2, v3, accY[dn]);
      }
    }
  }
  // epilogue: y = accY / lsum, split x3, store bf16 planes
  #pragma unroll
  for (int dn = 0; dn < 4; ++dn)
    #pragma unroll
    for (int j = 0; j < 4; ++j) {
      size_t row = (size_t)(b*1024 + qt*64 + w*16 + lgp*4 + j);
      float yv = accY[dn][j] / lsum[j];
      short s1, s2, s3; split3_1(yv, s1, s2, s3);
      size_t off = row*1024 + h*64 + dn*16 + lrow;
      y3[off] = s1;
      y3[psY + off] = s2;
      y3[2*psY + off] = s3;
    }
}

// ---------------- gate: fp32 LN + fp32 logits + softmax + top2 ----------------
__global__ __launch_bounds__(256) void gate_kernel(
    const float* __restrict__ X, const float* __restrict__ gam, const float* __restrict__ bet,
    const float* __restrict__ gw, const float* __restrict__ gb,
    float* __restrict__ score, int* __restrict__ topk_e, int* __restrict__ counts) {
  const int w = threadIdx.x >> 6, lane = threadIdx.x & 63;
  const int t = blockIdx.x * 4 + w;
  const float* xr = X + (size_t)t * 1024;
  float x[16];
  float s = 0.f, s2 = 0.f;
  #pragma unroll
  for (int j = 0; j < 16; ++j) {
    float u = xr[lane + 64*j];
    x[j] = u; s += u; s2 += u*u;
  }
  #pragma unroll
  for (int d = 1; d < 64; d <<= 1) { s += __shfl_xor(s, d); s2 += __shfl_xor(s2, d); }
  float mean = s * 0.0009765625f;
  float var = s2 * 0.0009765625f - mean*mean;
  float inv = rsqrtf(var + 1e-5f);
  #pragma unroll
  for (int j = 0; j < 16; ++j)
    x[j] = (x[j] - mean) * inv * gam[lane + 64*j] + bet[lane + 64*j];
  float lgt[8];
  #pragma unroll
  for (int e = 0; e < 8; ++e) {
    const float* wr = gw + e*1024;
    float a = 0.f;
    #pragma unroll
    for (int j = 0; j < 16; ++j) a += x[j] * wr[lane + 64*j];
    #pragma unroll
    for (int d = 1; d < 64; d <<= 1) a += __shfl_xor(a, d);
    lgt[e] = a + gb[e];
  }
  if (lane == 0) {
    int e0 = 0; float m0v = lgt[0];
    #pragma unroll
    for (int e = 1; e < 8; ++e) if (lgt[e] > m0v) { m0v = lgt[e]; e0 = e; }
    float den = 0.f;
    #pragma unroll
    for (int e = 0; e < 8; ++e) den += __expf(lgt[e] - m0v);
    int e1 = -1; float m1v = -1e30f;
    #pragma unroll
    for (int e = 0; e < 8; ++e) if (e != e0 && lgt[e] > m1v) { m1v = lgt[e]; e1 = e; }
    score[t*2+0] = 1.0f / den;
    score[t*2+1] = __expf(m1v - m0v) / den;
    topk_e[t*2+0] = e0;
    topk_e[t*2+1] = e1;
    atomicAdd(&counts[e0], 1);
    atomicAdd(&counts[e1], 1);
  }
}

__global__ void prefix_kernel(const int* __restrict__ counts, int* __restrict__ offs) {
  if (threadIdx.x == 0 && blockIdx.x == 0) {
    int o = 0;
    for (int e = 0; e < 8; ++e) { offs[e] = o; o += counts[e]; }
    offs[8] = o;
  }
}

__global__ __launch_bounds__(256) void scatter_kernel(
    const int* __restrict__ topk_e, const int* __restrict__ offs,
    int* __restrict__ counts2, int* __restrict__ slot_src) {
  int t = blockIdx.x * 256 + threadIdx.x;
  #pragma unroll
  for (int k = 0; k < 2; ++k) {
    int e = topk_e[t*2 + k];
    int pos = offs[e] + atomicAdd(&counts2[e], 1);
    slot_src[pos] = t*2 + k;
  }
}

// ---------------- single-plane bf16 GEMM K-loop (experts) ----------------
DEV void gemm_kloop(const short* ga0, const short* ga1,
                    const short* gb0, const short* gb1,
                    short* As, short* Bs,
                    int nk, int w, int lane, f32x4 acc[4][4]) {
  const int lrow = lane & 15, lk8 = (lane >> 4) * 8;
  const int wr = w >> 1, wc = w & 1;
  short* dA0 = As + (w * 128) * 8;
  short* dA1 = As + (w * 128 + 64) * 8;
  short* dB0 = Bs + (w * 128) * 8;
  short* dB1 = Bs + (w * 128 + 64) * 8;
  for (int kt = 0; kt < nk; ++kt) {
    __syncthreads();
    gll16(ga0, dA0); gll16(ga1, dA1);
    gll16(gb0, dB0); gll16(gb1, dB1);
    ga0 += 32; ga1 += 32; gb0 += 32; gb1 += 32;
    asm volatile("s_waitcnt vmcnt(0)" ::: "memory");
    __syncthreads();
    bf16x8 a[4], b[4];
    #pragma unroll
    for (int m = 0; m < 4; ++m)
      a[m] = *(const bf16x8*)(As + (wr*64 + m*16 + lrow)*32 + lk8);
    #pragma unroll
    for (int n = 0; n < 4; ++n)
      b[n] = *(const bf16x8*)(Bs + (wc*64 + n*16 + lrow)*32 + lk8);
    #pragma unroll
    for (int m = 0; m < 4; ++m)
      #pragma unroll
      for (int n = 0; n < 4; ++n)
        acc[m][n] = mfma16(a[m], b[n], acc[m][n]);
  }
}

// ---------------- MoE FC: gathered-A GEMM, gelu(acc + fc_b) -> h1buf ----------------
__global__ __launch_bounds__(256) void moe_fc(
    const short* __restrict__ h2, const short* __restrict__ Wfc,
    const int* __restrict__ offs, const int* __restrict__ slot_src,
    const float* __restrict__ fcb, short* __restrict__ h1buf) {
  const int e = blockIdx.z;
  const int base = offs[e], cnt = offs[e+1] - base;
  const int rt = blockIdx.y;
  if (rt * 128 >= cnt) return;
  const int n0 = blockIdx.x * 128;
  __shared__ short As[128*32], Bs[128*32];
  __shared__ int tokrow[128];
  const int tid = threadIdx.x, w = tid >> 6, lane = tid & 63;
  if (tid < 128) {
    int r = rt*128 + tid;
    int sv = slot_src[base + ((r < cnt) ? r : 0)];
    tokrow[tid] = sv >> 1;
  }
  __syncthreads();
  const int c0 = w*128 + lane, c1 = c0 + 64;
  const short* ga0 = h2 + (size_t)tokrow[c0 >> 2] * 1024 + (c0 & 3) * 8;
  const short* ga1 = h2 + (size_t)tokrow[c1 >> 2] * 1024 + (c1 & 3) * 8;
  const short* Be = Wfc + (size_t)e * 4096 * 1024;
  const short* gb0 = Be + (size_t)(n0 + (c0 >> 2)) * 1024 + (c0 & 3) * 8;
  const short* gb1 = Be + (size_t)(n0 + (c1 >> 2)) * 1024 + (c1 & 3) * 8;
  f32x4 acc[4][4];
  #pragma unroll
  for (int m=0;m<4;++m)
    #pragma unroll
    for(int n=0;n<4;++n) acc[m][n] = f32x4{0.f,0.f,0.f,0.f};
  gemm_kloop(ga0, ga1, gb0, gb1, As, Bs, 32, w, lane, acc);
  const int wr=w>>1, wc=w&1, lrow=lane&15, lgp=lane>>4;
  const float* fb = fcb + (size_t)e * 4096;
  #pragma unroll
  for (int m=0;m<4;++m)
    #pragma unroll
    for (int n=0;n<4;++n)
      #pragma unroll
      for (int j=0;j<4;++j) {
        int r = wr*64 + m*16 + lgp*4 + j;
        if (rt*128 + r < cnt) {
          int col = n0 + wc*64 + n*16 + lrow;
          float v = acc[m][n][j] + fb[col];
          h1buf[(size_t)(base + rt*128 + r) * 4096 + col] = f2bf(gelu_exact(v));
        }
      }
}

// ---------------- MoE PJ: epilogue atomicAdd(score*(acc+pj_b)) into out ----------------
__global__ __launch_bounds__(256) void moe_pj(
    const short* __restrict__ h1buf, const short* __restrict__ Wpj,
    const int* __restrict__ offs, const int* __restrict__ slot_src,
    const float* __restrict__ score, const float* __restrict__ pjb,
    float* __restrict__ out) {
  const int e = blockIdx.z;
  const int base = offs[e], cnt = offs[e+1] - base;
  const int rt = blockIdx.y;
  if (rt * 128 >= cnt) return;
  const int n0 = blockIdx.x * 128;
  __shared__ short As[128*32], Bs[128*32];
  __shared__ int tok[128];
  __shared__ float sc[128];
  const int tid = threadIdx.x, w = tid >> 6, lane = tid & 63;
  if (tid < 128) {
    int r = rt*128 + tid;
    int sv = slot_src[base + ((r < cnt) ? r : 0)];
    tok[tid] = sv >> 1;
    sc[tid] = score[sv];
  }
  __syncthreads();
  const int c0 = w*128 + lane, c1 = c0 + 64;
  const short* Ab = h1buf + (size_t)(base + rt*128) * 4096;
  const short* ga0 = Ab + (size_t)(c0 >> 2) * 4096 + (c0 & 3) * 8;
  const short* ga1 = Ab + (size_t)(c1 >> 2) * 4096 + (c1 & 3) * 8;
  const short* Be = Wpj + (size_t)e * 1024 * 4096;
  const short* gb0 = Be + (size_t)(n0 + (c0 >> 2)) * 4096 + (c0 & 3) * 8;
  const short* gb1 = Be + (size_t)(n0 + (c1 >> 2)) * 4096 + (c1 & 3) * 8;
  f32x4 acc[4][4];
  #pragma unroll
  for (int m=0;m<4;++m)
    #pragma unroll
    for(int n=0;n<4;++n) acc[m][n] = f32x4{0.f,0.f,0.f,0.f};
  gemm_kloop(ga0, ga1, gb0, gb1, As, Bs, 128, w, lane, acc);
  const int wr=w>>1, wc=w&1, lrow=lane&15, lgp=lane>>4;
  const float* pb = pjb + (size_t)e * 1024;
  #pragma unroll
  for (int m=0;m<4;++m)
    #pragma unroll
    for (int n=0;n<4;++n)
      #pragma unroll
      for (int j=0;j<4;++j) {
        int r = wr*64 + m*16 + lgp*4 + j;
        if (rt*128 + r < cnt) {
          int col = n0 + wc*64 + n*16 + lrow;
          float v = acc[m][n][j] + pb[col];
          atomicAdd(out + (size_t)tok[r] * 1024 + col, sc[r] * v);
        }
      }
}

extern "C" void kernel_launch(void* const* d_in, const int* in_sizes, int n_in,
                              void* d_out, int out_size, void* d_ws, size_t ws_size,
                              hipStream_t stream) {
  (void)in_sizes; (void)n_in; (void)out_size; (void)ws_size;
  const float* x      = (const float*)d_in[0];
  const float* ln1_g  = (const float*)d_in[1];
  const float* ln1_b  = (const float*)d_in[2];
  const float* Wq     = (const float*)d_in[3];
  const float* Wk     = (const float*)d_in[4];
  const float* Wv     = (const float*)d_in[5];
  const float* Wo     = (const float*)d_in[6];
  const float* bo     = (const float*)d_in[7];
  const float* ln2_g  = (const float*)d_in[8];
  const float* ln2_b  = (const float*)d_in[9];
  const float* gate_W = (const float*)d_in[10];
  const float* gate_b = (const float*)d_in[11];
  const float* fc_W   = (const float*)d_in[12];
  const float* fc_b   = (const float*)d_in[13];
  const float* pj_W   = (const float*)d_in[14];
  const float* pj_b   = (const float*)d_in[15];
  float* out = (float*)d_out;

  char* p = (char*)d_ws;
  auto alloc = [&](size_t bytes) { char* r = p; p += (bytes + 255) & ~(size_t)255; return r; };
  // persistent across the whole call
  short* Wfc    = (short*)alloc((size_t)8*4096*1024*2);   // 64 MB
  short* Wpj    = (short*)alloc((size_t)8*1024*4096*2);   // 64 MB
  short* h2b    = (short*)alloc((size_t)4096*1024*2);     // 8 MB
  float* score  = (float*)alloc(8192*4);
  int* topk_e   = (int*)alloc(8192*4);
  int* slot_src = (int*)alloc(8192*4);
  int* counts   = (int*)alloc(256);
  int* counts2  = counts + 16;
  int* offs     = counts + 32;
  // region A (100.7 MB), phase-aliased:
  //   attention phase: qkv | h1a3 (later reused as y3) | Wqkv3 | Wob3
  //   MoE phase:       h1moe aliases the whole region (68.2 MB <= 100.7 MB)
  char* rA = alloc((size_t)100663296);
  float* qkv   = (float*)rA;                       // 4096*3072*4   = 50331648
  short* h1a3  = (short*)(rA + 50331648);          // 3*4096*1024*2 = 25165824
  short* Wqkv3 = (short*)(rA + 75497472);          // 3*3072*1024*2 = 18874368
  short* Wob3  = (short*)(rA + 94371840);          // 3*1024*1024*2 = 6291456
  short* y3    = h1a3;    // h1a3 dead after gemm3<0>; attn writes y3 afterwards
  short* h1moe = (short*)rA;

  const size_t PS_H = (size_t)4096*1024;   // token-plane stride
  const size_t PS_QKV = (size_t)3072*1024; // Wqkv plane stride
  const size_t PS_O = (size_t)1024*1024;

  // weight conversions
  split_kernel<<<512, 256, 0, stream>>>(Wq, Wqkv3, PS_QKV, 131072);
  split_kernel<<<512, 256, 0, stream>>>(Wk, Wqkv3 + 1024*1024, PS_QKV, 131072);
  split_kernel<<<512, 256, 0, stream>>>(Wv, Wqkv3 + 2*1024*1024, PS_QKV, 131072);
  split_kernel<<<512, 256, 0, stream>>>(Wo, Wob3, PS_O, 131072);
  convert_kernel<<<16384, 256, 0, stream>>>(fc_W, Wfc, 4194304);
  convert_kernel<<<16384, 256, 0, stream>>>(pj_W, Wpj, 4194304);

  // attention path (bf16x3 everywhere)
  ln_kernel<3><<<4096, 256, 0, stream>>>(x, ln1_g, ln1_b, h1a3, PS_H);
  gemm3<0><<<dim3(24, 32), 256, 0, stream>>>(h1a3, Wqkv3, PS_H, PS_QKV,
                                             1024, 1024, 32, qkv, 3072, nullptr, nullptr);
  attn_kernel<<<dim3(16, 16, 4), 256, 0, stream>>>(qkv, y3, PS_H);
  gemm3<1><<<dim3(8, 32), 256, 0, stream>>>(y3, Wob3, PS_H, PS_O,
                                            1024, 1024, 32, out, 1024, x, bo);

  // MoE path (routing in fp32; experts in bf16)
  ln_kernel<1><<<4096, 256, 0, stream>>>(out, ln2_g, ln2_b, h2b, 0);
  hipMemsetAsync(counts, 0, 256, stream);
  gate_kernel<<<1024, 256, 0, stream>>>(out, ln2_g, ln2_b, gate_W, gate_b,
                                        score, topk_e, counts);
  prefix_kernel<<<1, 64, 0, stream>>>(counts, offs);
  scatter_kernel<<<16, 256, 0, stream>>>(topk_e, offs, counts2, slot_src);
  moe_fc<<<dim3(32, 64, 8), 256, 0, stream>>>(h2b, Wfc, offs, slot_src, fc_b, h1moe);
  moe_pj<<<dim3(8, 64, 8), 256, 0, stream>>>(h1moe, Wpj, offs, slot_src, score, pj_b, out);
}